// Round 1
// baseline (442.486 us; speedup 1.0000x reference)
//
#include <hip/hip_runtime.h>
#include <cmath>

#define LBINS 401
#define LL (LBINS * LBINS)
#define MIN_SEP 2

// accum (float) workspace layout
#define ACC_HANY    401
#define ACC_HCONV   402
#define ACC_SMASK   403
#define ACC_SWITHIN 404
#define ACC_COUNT   408   // floats to zero; flags byte array follows

// ---------------------------------------------------------------------------
// Kernel 1: zero accumulators + pack per-(b,l) flags.
// bit0 = ctcf==1 (forward), bit1 = ctcf==-1 (reverse), bit2 = ctcf!=0 (any),
// bit3 = argmax(compartment_logits) (tie -> 0, so comp=1 iff l1 > l0)
// ---------------------------------------------------------------------------
__global__ void prep_kernel(const int* __restrict__ ctcf,
                            const float* __restrict__ logits,
                            float* __restrict__ accum,
                            unsigned char* __restrict__ flags,
                            int BL) {
    int t = blockIdx.x * blockDim.x + threadIdx.x;
    if (t < ACC_COUNT) accum[t] = 0.0f;
    if (t < BL) {
        int o = ctcf[t];
        unsigned char f = 0;
        if (o == 1)  f |= 1;
        if (o == -1) f |= 2;
        if (o != 0)  f |= 4;
        float l0 = logits[2 * t + 0];
        float l1 = logits[2 * t + 1];
        if (l1 > l0) f |= 8;
        flags[t] = f;
    }
}

// ---------------------------------------------------------------------------
// Kernel 2: one pass over contact_map (B*L*L fp32, ~165 MB) — HBM-bound.
// ---------------------------------------------------------------------------
__device__ __forceinline__ void accumulate_elem(
    float val, int s, unsigned char fi, unsigned char fj,
    float& h_any, float& h_conv, float& s_mask, float& s_within,
    float* lbins) {
    atomicAdd(&lbins[s], val);              // LDS atomic, mostly conflict-free
    float rc = fmaxf(val, 0.0f);
    if (fi & fj & 4) {                       // any_i && any_j
        h_any += rc;
        if ((fi & 1) && (fj & 2)) h_conv += rc;  // forward_i && reverse_j
    }
    if (s >= MIN_SEP) {
        s_mask += val;
        if (((fi ^ fj) & 8) == 0) s_within += val;  // same compartment
    }
}

__global__ __launch_bounds__(256)
void main_kernel(const float* __restrict__ cm,
                 const unsigned char* __restrict__ flags,
                 float* __restrict__ accum,
                 int total) {
    __shared__ float lbins[LBINS];
    __shared__ float wred[4][8];
    for (int s = threadIdx.x; s < LBINS; s += blockDim.x) lbins[s] = 0.0f;
    __syncthreads();

    float h_any = 0.f, h_conv = 0.f, sm = 0.f, sw = 0.f;

    int nvec = total >> 2;
    int gid = blockIdx.x * blockDim.x + threadIdx.x;
    int gstride = gridDim.x * blockDim.x;
    const float4* __restrict__ cm4 = (const float4*)cm;

    for (int v = gid; v < nvec; v += gstride) {
        float4 c = cm4[v];
        unsigned int t = ((unsigned int)v) << 2;
        unsigned int b = t / LL;
        unsigned int rem = t - b * LL;
        unsigned int i = rem / LBINS;
        unsigned int j = rem - i * LBINS;
        float cv[4] = {c.x, c.y, c.z, c.w};
        const unsigned char* browf = flags + b * LBINS;
        if (j + 3u < LBINS) {               // fast path: all 4 in one row
            unsigned char fi = browf[i];
            #pragma unroll
            for (int k = 0; k < 4; ++k) {
                int jj = (int)j + k;
                int s = (int)i - jj; s = s < 0 ? -s : s;
                accumulate_elem(cv[k], s, fi, browf[jj], h_any, h_conv, sm, sw, lbins);
            }
        } else {                            // row/batch wrap
            #pragma unroll
            for (int k = 0; k < 4; ++k) {
                unsigned int jj = j + (unsigned)k, ii = i, bb = b;
                if (jj >= LBINS) { jj -= LBINS; ii += 1; if (ii >= LBINS) { ii = 0; bb += 1; } }
                int s = (int)ii - (int)jj; s = s < 0 ? -s : s;
                const unsigned char* bf = flags + bb * LBINS;
                accumulate_elem(cv[k], s, bf[ii], bf[jj], h_any, h_conv, sm, sw, lbins);
            }
        }
    }
    // scalar tail (total % 4 != 0)
    for (int t = (nvec << 2) + gid; t < total; t += gstride) {
        unsigned int b = (unsigned int)t / LL;
        unsigned int rem = (unsigned int)t - b * LL;
        unsigned int i = rem / LBINS;
        unsigned int j = rem - i * LBINS;
        int s = (int)i - (int)j; s = s < 0 ? -s : s;
        const unsigned char* bf = flags + b * LBINS;
        accumulate_elem(cm[t], s, bf[i], bf[j], h_any, h_conv, sm, sw, lbins);
    }

    // wave reduce (64-lane) then cross-wave via LDS
    #pragma unroll
    for (int off = 32; off > 0; off >>= 1) {
        h_any  += __shfl_down(h_any,  off, 64);
        h_conv += __shfl_down(h_conv, off, 64);
        sm     += __shfl_down(sm,     off, 64);
        sw     += __shfl_down(sw,     off, 64);
    }
    int wave = threadIdx.x >> 6;
    int lane = threadIdx.x & 63;
    if (lane == 0) {
        wred[0][wave] = h_any; wred[1][wave] = h_conv;
        wred[2][wave] = sm;    wred[3][wave] = sw;
    }
    __syncthreads();
    if (threadIdx.x == 0) {
        int nw = blockDim.x >> 6;
        float a = 0.f, b2 = 0.f, cc = 0.f, dd = 0.f;
        for (int w2 = 0; w2 < nw; ++w2) {
            a += wred[0][w2]; b2 += wred[1][w2]; cc += wred[2][w2]; dd += wred[3][w2];
        }
        unsafeAtomicAdd(&accum[ACC_HANY], a);
        unsafeAtomicAdd(&accum[ACC_HCONV], b2);
        unsafeAtomicAdd(&accum[ACC_SMASK], cc);
        unsafeAtomicAdd(&accum[ACC_SWITHIN], dd);
    }
    for (int s = threadIdx.x; s < LBINS; s += blockDim.x)
        unsafeAtomicAdd(&accum[s], lbins[s]);
}

// ---------------------------------------------------------------------------
// Kernel 3: finalize (single block).
// ---------------------------------------------------------------------------
__device__ double block_reduce_d(double v, double* buf) {
    int tid = threadIdx.x;
    buf[tid] = v;
    __syncthreads();
    for (int off = blockDim.x >> 1; off > 0; off >>= 1) {
        if (tid < off) buf[tid] += buf[tid + off];
        __syncthreads();
    }
    double r = buf[0];
    __syncthreads();
    return r;
}

__global__ __launch_bounds__(512)
void final_kernel(const unsigned char* __restrict__ flags,
                  const float* __restrict__ accum,
                  float* __restrict__ out, int B) {
    __shared__ double dred[512];
    int tid = threadIdx.x;

    // ---- per-batch closed-form counts ----
    double nc_local = 0.0, same_local = 0.0;
    for (int b = tid; b < B; b += blockDim.x) {
        const unsigned char* bf = flags + b * LBINS;
        int n1 = 0, nf = 0, nr = 0, na = 0, adj = 0, prev = 0;
        for (int l = 0; l < LBINS; ++l) {
            int f = bf[l];
            int comp = (f >> 3) & 1;
            n1 += comp;
            nf += f & 1;
            nr += (f >> 1) & 1;
            na += (f >> 2) & 1;
            adj += (l > 0 && comp == prev) ? 1 : 0;
            prev = comp;
        }
        int n0 = LBINS - n1;
        nc_local   += (double)na * na - (double)nf * nr;
        same_local += (double)n0 * n0 + (double)n1 * n1 - (double)LBINS - 2.0 * adj;
    }
    double nc_sum   = block_reduce_d(nc_local, dred);
    double same_cnt = block_reduce_d(same_local, dred);
    double total_maskf = (double)B * ((double)LL - 3.0 * LBINS + 2.0);
    double diff_cnt = total_maskf - same_cnt;

    // ---- distance-decay regression over 401 bins ----
    float w = 0.f, x = 0.f, y = 0.f;
    if (tid < LBINS) {
        float cntB = ((tid == 0) ? (float)LBINS : 2.0f * (float)(LBINS - tid)) * (float)B;
        float mc = accum[tid] / cntB;
        int valid = (tid >= MIN_SEP) && __builtin_isfinite(mc) && (mc > 0.0f);
        w = valid ? 1.f : 0.f;
        x = logf(fmaxf((float)tid, 1.0f));
        y = logf((valid ? mc : 1.0f) + 1e-6f);
    }
    double n  = block_reduce_d((double)w, dred);
    double Sx = block_reduce_d((double)w * x, dred);
    double Sy = block_reduce_d((double)w * y, dred);
    double n_safe = fmax(n, 1.0);
    double xm = Sx / n_safe, ym = Sy / n_safe;
    double num = block_reduce_d((double)w * ((double)x - xm) * ((double)y - ym), dred);
    double den = block_reduce_d((double)w * ((double)x - xm) * ((double)x - xm), dred);

    if (tid == 0) {
        double slope = num / (den + 1e-8);
        float dist_loss = (n >= 5.0) ? (float)((slope + 0.85) * (slope + 0.85)) : 0.0f;

        float hinge_nonconv = accum[ACC_HANY] - accum[ACC_HCONV];
        float ncf = (float)nc_sum;
        float hinge = hinge_nonconv / (ncf + 1e-6f);
        float ctcf_loss = (ncf < 1.0f) ? 0.0f : hinge;

        float within  = accum[ACC_SWITHIN] / (float)fmax(same_cnt, 1.0);
        float between = (accum[ACC_SMASK] - accum[ACC_SWITHIN]) / (float)fmax(diff_cnt, 1.0);
        float ratio = within / (fabsf(between) + 1e-6f);
        float comp_loss = fmaxf(1.5f - ratio, 0.0f);

        float total = 1.0f * dist_loss + 0.5f * ctcf_loss + 0.5f * comp_loss;
        out[0] = dist_loss;
        out[1] = ctcf_loss;
        out[2] = comp_loss;
        out[3] = total;
    }
}

// ---------------------------------------------------------------------------
extern "C" void kernel_launch(void* const* d_in, const int* in_sizes, int n_in,
                              void* d_out, int out_size, void* d_ws, size_t ws_size,
                              hipStream_t stream) {
    const float* cm     = (const float*)d_in[0];   // (B, L, L) fp32
    const float* logits = (const float*)d_in[1];   // (B, L, 2) fp32
    const int*   ctcf   = (const int*)d_in[2];     // (B, L) int32
    float* out = (float*)d_out;

    int total = in_sizes[0];
    int B = total / LL;
    int BL = B * LBINS;

    float* accum = (float*)d_ws;
    unsigned char* flags = (unsigned char*)d_ws + ACC_COUNT * sizeof(float);

    int prep_threads = 256;
    int prep_work = BL > ACC_COUNT ? BL : ACC_COUNT;
    int prep_blocks = (prep_work + prep_threads - 1) / prep_threads;
    prep_kernel<<<prep_blocks, prep_threads, 0, stream>>>(ctcf, logits, accum, flags, BL);

    main_kernel<<<2048, 256, 0, stream>>>(cm, flags, accum, total);

    final_kernel<<<1, 512, 0, stream>>>(flags, accum, out, B);
}